// Round 12
// baseline (158.257 us; speedup 1.0000x reference)
//
#include <hip/hip_runtime.h>
#include <hip/hip_bf16.h>

typedef float f32x4 __attribute__((ext_vector_type(4)));
typedef float f32x16 __attribute__((ext_vector_type(16)));
typedef __bf16 bf16x8 __attribute__((ext_vector_type(8)));
typedef unsigned short us8 __attribute__((ext_vector_type(8)));
typedef unsigned short us4 __attribute__((ext_vector_type(4)));

#define DEVI __device__ __forceinline__
#define LOG2E 1.44269504088896f

DEVI unsigned short f2bf(float x) {
  return __builtin_bit_cast(unsigned short, __float2bfloat16(x));
}
DEVI float bf2f(unsigned short u) {
  return __builtin_bit_cast(float, ((unsigned int)u) << 16);
}
DEVI bf16x8 ldb8(const unsigned short* p) {
  return __builtin_bit_cast(bf16x8, *(const us8*)p);
}
DEVI void gload16(const unsigned short* g, unsigned short* l) {
  __builtin_amdgcn_global_load_lds(
      (const __attribute__((address_space(1))) unsigned int*)(const void*)g,
      (__attribute__((address_space(3))) unsigned int*)(void*)l, 16, 0, 0);
}

// ---------------- fp32 -> bf16 converts ----------------
__global__ __launch_bounds__(256) void cvt3_k(const float* __restrict__ p0, const float* __restrict__ p1,
                                              const float* __restrict__ p2,
                                              unsigned short* __restrict__ o0, unsigned short* __restrict__ o1,
                                              unsigned short* __restrict__ o2, int n) {
  const float* in;
  unsigned short* out;
  switch (blockIdx.y) {
    case 0: in = p0; out = o0; break;
    case 1: in = p1; out = o1; break;
    default: in = p2; out = o2; break;
  }
  int i = (blockIdx.x * 256 + threadIdx.x) * 8;
  if (i >= n) return;
  float4 a = *(const float4*)(in + i);
  float4 b = *(const float4*)(in + i + 4);
  us8 r = {f2bf(a.x), f2bf(a.y), f2bf(a.z), f2bf(a.w), f2bf(b.x), f2bf(b.y), f2bf(b.z), f2bf(b.w)};
  *(us8*)(out + i) = r;
}

__global__ __launch_bounds__(256) void cvt5_k(const float* __restrict__ p0, const float* __restrict__ p1,
                                              const float* __restrict__ p2, const float* __restrict__ p3,
                                              const float* __restrict__ p4,
                                              unsigned short* __restrict__ o0, unsigned short* __restrict__ o1,
                                              unsigned short* __restrict__ o2, unsigned short* __restrict__ o3,
                                              unsigned short* __restrict__ o4) {
  const float* in;
  unsigned short* out;
  int n = 1048576;
  switch (blockIdx.y) {
    case 0: in = p0; out = o0; break;
    case 1: in = p1; out = o1; break;
    case 2: in = p2; out = o2; break;
    case 3: in = p3; out = o3; break;
    default: in = p4; out = o4; n = 524288; break;
  }
  int i = (blockIdx.x * 256 + threadIdx.x) * 8;
  if (i >= n) return;
  float4 a = *(const float4*)(in + i);
  float4 b = *(const float4*)(in + i + 4);
  us8 r = {f2bf(a.x), f2bf(a.y), f2bf(a.z), f2bf(a.w), f2bf(b.x), f2bf(b.y), f2bf(b.z), f2bf(b.w)};
  *(us8*)(out + i) = r;
}

// ---------------- zero-init for vad atomics (ws not re-poisoned between replays) ----------------
__global__ __launch_bounds__(256) void zero_k(float* __restrict__ a, float* __restrict__ b) {
  int i = blockIdx.x * 256 + threadIdx.x;   // 6144 float4 total (3072 each)
  if (i < 3072) ((float4*)a)[i] = float4{0.f, 0.f, 0.f, 0.f};
  else ((float4*)b)[i - 3072] = float4{0.f, 0.f, 0.f, 0.f};
}

// ---------------- GEMM body (R9-proven loop): BK=64, 32x32x16 MFMA, full row-bit swizzle ----------
// EPI: 0 = bf16 col-bias; 1 = GELU + fused vad2 partial (atomicAdd into Cout=float* vad, no C write);
//      2 = bf16 out, col-bias*0.5 (split-K half); 3 = bf16 ROW-bias
template <int EPI>
DEVI void gemm_body(const unsigned short* __restrict__ A, const unsigned short* __restrict__ W,
                    const float* __restrict__ bias, void* __restrict__ Cout,
                    int N, int K, int lda, float oscale, int brow, int bcol,
                    unsigned short* As, unsigned short* Bs, int t,
                    const float* __restrict__ w2) {
  const int l = t & 63;
  const int w4 = t >> 6, wr = w4 >> 1, wc = w4 & 1;
  const int l5 = l & 31, hi = l >> 5;
  f32x16 acc[2][2] = {};
  for (int kt = 0; kt < K; kt += 64) {
    __syncthreads();
#pragma unroll
    for (int i = 0; i < 4; ++i) {
      int c = t + i * 256;                     // 1024 chunks of 16B per operand
      int row = c >> 3;
      int sw = (((c & 7) ^ (row & 7) ^ ((row >> 3) & 3))) * 8;   // inverse-swizzled source
      gload16(A + (size_t)(brow + row) * lda + kt + sw, As + c * 8);
      gload16(W + (size_t)(bcol + row) * lda + kt + sw, Bs + c * 8);
    }
    __syncthreads();
#pragma unroll
    for (int ks = 0; ks < 4; ++ks) {           // 4 k-steps of 16
      bf16x8 af[2], bfr[2];
      const int ch = (ks * 2 + hi) ^ (l5 & 7) ^ ((l5 >> 3) & 3); // swizzled 16B chunk
#pragma unroll
      for (int mi = 0; mi < 2; ++mi)
        af[mi] = ldb8(&As[(wr * 64 + mi * 32 + l5) * 64 + ch * 8]);
#pragma unroll
      for (int ni = 0; ni < 2; ++ni)
        bfr[ni] = ldb8(&Bs[(wc * 64 + ni * 32 + l5) * 64 + ch * 8]);
#pragma unroll
      for (int mi = 0; mi < 2; ++mi)
#pragma unroll
        for (int ni = 0; ni < 2; ++ni)
          acc[mi][ni] = __builtin_amdgcn_mfma_f32_32x32x16_bf16(af[mi], bfr[ni], acc[mi][ni], 0, 0, 0);
    }
  }
  // C/D layout (m74/m101-verified): col = lane&31, row = (reg&3) + 8*(reg>>2) + 4*(lane>>5)
  if (EPI == 1) {
    // GELU -> LDS transpose (reuse As/Bs: [128 rows][64 cols] each) -> per-row dot w2 -> atomicAdd
    __syncthreads();   // all waves done with K-loop LDS reads
    unsigned short* half = wc ? Bs : As;   // wc=0 covers cols 0-63, wc=1 covers 64-127
#pragma unroll
    for (int mi = 0; mi < 2; ++mi)
#pragma unroll
      for (int ni = 0; ni < 2; ++ni) {
        int colL = ni * 32 + l5;            // 0..63 within half
        float bc = bias[bcol + wc * 64 + colL];
#pragma unroll
        for (int reg = 0; reg < 16; ++reg) {
          int rowL = wr * 64 + mi * 32 + hi * 4 + (reg & 3) + 8 * (reg >> 2);
          float v = acc[mi][ni][reg] + bc;
          v = 0.5f * v * (1.0f + erff(v * 0.70710678118f));
          half[rowL * 64 + colL] = f2bf(v);
        }
      }
    __syncthreads();
    // 256 threads: thread t -> row=t>>1, colHalf=t&1; dot 64 gelu values with w2[3][512]
    const int row = t >> 1, ch2 = t & 1;
    const unsigned short* src = ch2 ? Bs : As;
    const float* w2c = w2 + bcol + ch2 * 64;
    float s0 = 0.f, s1 = 0.f, s2 = 0.f;
#pragma unroll
    for (int jq = 0; jq < 8; ++jq) {
      us8 gv = *(const us8*)(src + row * 64 + jq * 8);
#pragma unroll
      for (int j = 0; j < 8; ++j) {
        float g = bf2f(gv[j]);
        int col = jq * 8 + j;
        s0 += g * w2c[col];
        s1 += g * w2c[512 + col];
        s2 += g * w2c[1024 + col];
      }
    }
    s0 += __shfl_xor(s0, 1, 64);
    s1 += __shfl_xor(s1, 1, 64);
    s2 += __shfl_xor(s2, 1, 64);
    if (!ch2) {
      float* vp = (float*)Cout + (size_t)(brow + row) * 3;
      atomicAdd(vp, s0);
      atomicAdd(vp + 1, s1);
      atomicAdd(vp + 2, s2);
    }
    return;
  }
#pragma unroll
  for (int mi = 0; mi < 2; ++mi)
#pragma unroll
    for (int ni = 0; ni < 2; ++ni) {
      int col = bcol + wc * 64 + ni * 32 + l5;
      int rowBase = brow + wr * 64 + mi * 32 + hi * 4;
      float bc = (EPI == 3) ? 0.f : bias[col];
#pragma unroll
      for (int reg = 0; reg < 16; ++reg) {
        int row = rowBase + (reg & 3) + 8 * (reg >> 2);
        float v;
        if (EPI == 3)
          v = (acc[mi][ni][reg] + bias[row]) * oscale;
        else if (EPI == 2)
          v = acc[mi][ni][reg] + 0.5f * bc;
        else
          v = (acc[mi][ni][reg] + bc) * oscale;
        ((unsigned short*)Cout)[(size_t)row * N + col] = f2bf(v);
      }
    }
}

// ---------------- fused projections: Q-proj | K-proj | V^T | h1q+vad | h1k+vad in one launch ----------------
__global__ __launch_bounds__(256) void proj_k(const unsigned short* __restrict__ qb, const unsigned short* __restrict__ kb,
                                              const unsigned short* __restrict__ vb,
                                              const unsigned short* __restrict__ wqb, const unsigned short* __restrict__ wkb,
                                              const unsigned short* __restrict__ wvb, const unsigned short* __restrict__ w1b,
                                              const float* __restrict__ bq, const float* __restrict__ bk,
                                              const float* __restrict__ bv, const float* __restrict__ b1,
                                              const float* __restrict__ w2,
                                              unsigned short* __restrict__ Qp, unsigned short* __restrict__ Kp,
                                              unsigned short* __restrict__ Vt,
                                              float* __restrict__ vadq, float* __restrict__ vadk) {
  __shared__ unsigned short As[8192];
  __shared__ unsigned short Bs[8192];
  const int t = threadIdx.x;
  const int lin = blockIdx.x;                 // 1024 blocks
  const int nl = (lin & 7) * 128 + (lin >> 3);  // XCD swizzle: each XCD gets one contiguous range
  if (nl < 256) {        // Q projection (pre-scaled by SCALE*log2e), 8x32
    gemm_body<0>(qb, wqb, bq, Qp, 1024, 1024, 1024, 0.125f * LOG2E,
                 (nl >> 3) * 128, (nl & 7) * 128, As, Bs, t, nullptr);
  } else if (nl < 512) { // K projection, 8x32
    int s = nl - 256;
    gemm_body<0>(kb, wkb, bk, Kp, 1024, 1024, 1024, 1.f,
                 (s >> 3) * 128, (s & 7) * 128, As, Bs, t, nullptr);
  } else if (nl < 768) { // V^T = Wv @ X^T (row-bias), 32x8
    int s = nl - 512;
    gemm_body<3>(wvb, vb, bv, Vt, 4096, 1024, 1024, 1.f,
                 (s >> 5) * 128, (s & 31) * 128, As, Bs, t, nullptr);
  } else {               // VAD layer 1 (GELU) + fused layer-2 partials, 4x32 x2
    int s = nl - 768;
    const unsigned short* A = (s >= 128) ? kb : qb;
    float* V = (s >= 128) ? vadk : vadq;
    int s2 = s & 127;
    gemm_body<1>(A, w1b, b1, V, 512, 1024, 1024, 1.f,
                 (s2 >> 2) * 128, (s2 & 3) * 128, As, Bs, t, w2);
  }
}

// ---------------- Wo GEMM, split-K x2 (512 blocks), bf16 partial outputs ----------------
__global__ __launch_bounds__(256) void wo_k(const unsigned short* __restrict__ Obuf, const unsigned short* __restrict__ wob,
                                            const float* __restrict__ bo,
                                            unsigned short* __restrict__ tmpA, unsigned short* __restrict__ tmpB) {
  __shared__ unsigned short As[8192];
  __shared__ unsigned short Bs[8192];
  const int t = threadIdx.x;
  const int lin = blockIdx.x;                 // 512 blocks
  const int nl = (lin & 7) * 64 + (lin >> 3);
  const int z = nl >> 8, s = nl & 255;
  gemm_body<2>(Obuf + z * 512, wob + z * 512, bo, z ? tmpB : tmpA,
               1024, 512, 1024, 1.f, (s >> 3) * 128, (s & 7) * 128, As, Bs, t, nullptr);
}

// ---------------- affinity precompute, q-major + log2e-scaled: aff[b][q][k]; tanh+b2 applied here ----
__global__ __launch_bounds__(256) void aff_k(const float* __restrict__ vq, const float* __restrict__ vk,
                                             const float* __restrict__ plam, const float* __restrict__ b2,
                                             unsigned short* __restrict__ aff) {
  __shared__ float vqs[64][3], vks[64][3];
  const int t = threadIdx.x;
  const int b = blockIdx.z, q0 = blockIdx.y * 64, k0 = blockIdx.x * 64;
  const float lam2 = plam[0] * LOG2E;
  if (t < 192) {
    float bb = b2[t % 3];
    ((float*)vqs)[t] = tanhf(vq[((size_t)b * 1024 + q0) * 3 + t] + bb);
    ((float*)vks)[t] = tanhf(vk[((size_t)b * 1024 + k0) * 3 + t] + bb);
  }
  __syncthreads();
  const int q = t >> 2, kc = (t & 3) * 16;
  const float a0 = vqs[q][0], a1 = vqs[q][1], a2 = vqs[q][2];
  unsigned short o[16];
#pragma unroll
  for (int j = 0; j < 16; ++j) {
    int k = kc + j;
    float dx = a0 - vks[k][0], dy = a1 - vks[k][1], dz = a2 - vks[k][2];
    o[j] = f2bf(-lam2 * sqrtf(dx * dx + dy * dy + dz * dz));
  }
  unsigned short* dst = aff + ((size_t)(b * 1024 + q0 + q)) * 1024 + k0 + kc;
  *(us8*)dst = *(us8*)&o[0];
  *(us8*)(dst + 8) = *(us8*)&o[8];
}

// ---------------- flash attention: QBLK=128, no-max exp2 softmax, aff as C-init; 3 blocks/CU ----------------
__global__ __launch_bounds__(512, 6) void attn_k(const unsigned short* __restrict__ Qp,
                                                 const unsigned short* __restrict__ Kp,
                                                 const unsigned short* __restrict__ Vt,
                                                 const unsigned short* __restrict__ aff,
                                                 unsigned short* __restrict__ Obuf) {
  __shared__ unsigned short Ks[2][4096];   // [64][64] bf16, chunk ^= row&7
  __shared__ unsigned short Vs[2][4096];   // logical [d][token]
  __shared__ unsigned short Ps[8][1024];   // per-wave [16 q-rows][64 k], 16B-chunk XOR-swizzled
  const int lin = blockIdx.x + 8 * (blockIdx.y + 16 * blockIdx.z);  // 512 blocks, grid (8,16,4)
  const int nl = (lin & 7) * 64 + (lin >> 3);  // XCD swizzle (512 = 8*64, bijective)
  const int qb = nl & 7, h = (nl >> 3) & 15, b = nl >> 7;
  const int t = threadIdx.x, l = t & 63, w = t >> 6;   // w in 0..7
  const int l4 = l & 15, lg = l >> 4;
  const size_t qrow0 = (size_t)b * 1024 + qb * 128;
  const int hoff = h * 64;

  // Q fragments straight to registers (read-once). Used as MFMA *B*-operand (swapped QK^T).
  bf16x8 qf[2];
#pragma unroll
  for (int ks = 0; ks < 2; ++ks)
    qf[ks] = ldb8(Qp + (qrow0 + w * 16 + l4) * 1024 + hoff + ks * 32 + lg * 8);

  // prologue: stage K/V tile 0 (512 threads -> 1 chunk each per operand)
  {
    const unsigned short* gk = Kp + ((size_t)b * 1024) * 1024 + hoff;
    const unsigned short* gv = Vt + (size_t)hoff * 4096 + (size_t)b * 1024;
    int c = t, row = c >> 3, sw = ((c & 7) ^ (row & 7)) * 8;
    gload16(gk + (size_t)row * 1024 + sw, Ks[0] + c * 8);
    gload16(gv + (size_t)row * 4096 + sw, Vs[0] + c * 8);
  }
  float l_run = 0.f;   // per-lane partial denominator (this lane's 16 k-columns per tile)
  f32x4 accO[4] = {};
  const unsigned short* ab = aff + (qrow0 + w * 16 + l4) * 1024 + lg * 4;
  __syncthreads();

  int cur = 0;
  for (int kt = 0; kt < 16; ++kt) {
    // issue next-tile stage FIRST: latency hides under this tile's compute
    if (kt < 15) {
      const unsigned short* gk = Kp + ((size_t)b * 1024 + (kt + 1) * 64) * 1024 + hoff;
      const unsigned short* gv = Vt + (size_t)hoff * 4096 + (size_t)b * 1024 + (kt + 1) * 64;
      int c = t, row = c >> 3, sw = ((c & 7) ^ (row & 7)) * 8;
      gload16(gk + (size_t)row * 1024 + sw, Ks[cur ^ 1] + c * 8);
      gload16(gv + (size_t)row * 4096 + sw, Vs[cur ^ 1] + c * 8);
    }
    // QK^T with SWAPPED operands, affinity as C-initializer:
    f32x4 sc[4];
#pragma unroll
    for (int jt = 0; jt < 4; ++jt) {
      us4 av = *(const us4*)(ab + kt * 64 + jt * 16);
#pragma unroll
      for (int r = 0; r < 4; ++r) sc[jt][r] = bf2f(av[r]);
    }
    __builtin_amdgcn_s_setprio(1);
#pragma unroll
    for (int jt = 0; jt < 4; ++jt) {
#pragma unroll
      for (int ks = 0; ks < 2; ++ks) {
        bf16x8 kf = ldb8(&Ks[cur][(jt * 16 + l4) * 64 + (((ks * 4 + lg) ^ (l4 & 7))) * 8]);
        sc[jt] = __builtin_amdgcn_mfma_f32_16x16x32_bf16(kf, qf[ks], sc[jt], 0, 0, 0);
      }
    }
    __builtin_amdgcn_s_setprio(0);
    // no-max softmax: scores bounded -> exp2 directly, f32-safe
    float pv[4][4];
    float rs = 0.f;
#pragma unroll
    for (int jt = 0; jt < 4; ++jt)
#pragma unroll
      for (int r = 0; r < 4; ++r) { pv[jt][r] = exp2f(sc[jt][r]); rs += pv[jt][r]; }
    l_run += rs;
    // pack P to bf16 pairs, swizzled ds_write_b64 into Ps[w][q=l4][k]
    char* pw = (char*)&Ps[w][0];
#pragma unroll
    for (int jt = 0; jt < 4; ++jt) {
      unsigned int p0, p1;
      asm("v_cvt_pk_bf16_f32 %0, %1, %2" : "=v"(p0) : "v"(pv[jt][0]), "v"(pv[jt][1]));
      asm("v_cvt_pk_bf16_f32 %0, %1, %2" : "=v"(p1) : "v"(pv[jt][2]), "v"(pv[jt][3]));
      int chunk = (jt * 2 + (lg >> 1)) ^ (l4 & 7);
      *(unsigned long long*)(pw + l4 * 128 + chunk * 16 + (lg & 1) * 8) =
          (unsigned long long)p0 | ((unsigned long long)p1 << 32);
    }
    // PV: A-frag from Ps (row=l4, k=lg*8+j), B-frag from transposed V
    __builtin_amdgcn_s_setprio(1);
#pragma unroll
    for (int js = 0; js < 2; ++js) {
      bf16x8 pa = ldb8(&Ps[w][l4 * 64 + (((js * 4 + lg) ^ (l4 & 7))) * 8]);
#pragma unroll
      for (int dt = 0; dt < 4; ++dt) {
        bf16x8 vf = ldb8(&Vs[cur][(dt * 16 + l4) * 64 + (((js * 4 + lg) ^ (l4 & 7))) * 8]);
        accO[dt] = __builtin_amdgcn_mfma_f32_16x16x32_bf16(pa, vf, accO[dt], 0, 0, 0);
      }
    }
    __builtin_amdgcn_s_setprio(0);
    __syncthreads();  // single barrier per tile
    cur ^= 1;
  }
  // epilogue: reduce denominator across lg groups, transpose to accO's q-domain, normalize
  l_run += __shfl_xor(l_run, 16, 64);
  l_run += __shfl_xor(l_run, 32, 64);
  float linv = 1.f / l_run;
  float lr[4];
#pragma unroll
  for (int r = 0; r < 4; ++r) lr[r] = __shfl(linv, lg * 4 + r, 16);
#pragma unroll
  for (int dt = 0; dt < 4; ++dt)
#pragma unroll
    for (int r = 0; r < 4; ++r) {
      float v = accO[dt][r] * lr[r];
      Obuf[(qrow0 + w * 16 + lg * 4 + r) * 1024 + hoff + dt * 16 + l4] = f2bf(v);
    }
}

// ---------------- residual + layernorm (query fp32 + bf16 partials tmpA + tmpB) ----------------
__global__ __launch_bounds__(256) void ln_k(const float* __restrict__ q,
                                            const unsigned short* __restrict__ ta,
                                            const unsigned short* __restrict__ tb,
                                            const float* __restrict__ g,
                                            const float* __restrict__ bb,
                                            float* __restrict__ out) {
  __shared__ float red[8];
  const int row = blockIdx.x, t = threadIdx.x;
  const int l = t & 63, w = t >> 6;
  const size_t base = (size_t)row * 1024 + t * 4;
  float4 a = *(const float4*)(q + base);
  us4 cv = *(const us4*)(ta + base);
  us4 dv = *(const us4*)(tb + base);
  float x0 = a.x + bf2f(cv[0]) + bf2f(dv[0]);
  float x1 = a.y + bf2f(cv[1]) + bf2f(dv[1]);
  float x2 = a.z + bf2f(cv[2]) + bf2f(dv[2]);
  float x3 = a.w + bf2f(cv[3]) + bf2f(dv[3]);
  float s = x0 + x1 + x2 + x3;
#pragma unroll
  for (int m = 1; m < 64; m <<= 1) s += __shfl_xor(s, m, 64);
  if (l == 0) red[w] = s;
  __syncthreads();
  float mean = (red[0] + red[1] + red[2] + red[3]) * (1.f / 1024.f);
  float d0 = x0 - mean, d1 = x1 - mean, d2 = x2 - mean, d3 = x3 - mean;
  float v = d0 * d0 + d1 * d1 + d2 * d2 + d3 * d3;
#pragma unroll
  for (int m = 1; m < 64; m <<= 1) v += __shfl_xor(v, m, 64);
  if (l == 0) red[4 + w] = v;
  __syncthreads();
  float var = (red[4] + red[5] + red[6] + red[7]) * (1.f / 1024.f);
  float rstd = rsqrtf(var + 1e-5f);
  float4 gv = *(const float4*)(g + t * 4);
  float4 bv = *(const float4*)(bb + t * 4);
  float4 o;
  o.x = d0 * rstd * gv.x + bv.x;
  o.y = d1 * rstd * gv.y + bv.y;
  o.z = d2 * rstd * gv.z + bv.z;
  o.w = d3 * rstd * gv.w + bv.w;
  *(float4*)(out + (size_t)row * 1024 + t * 4) = o;
}

extern "C" void kernel_launch(void* const* d_in, const int* in_sizes, int n_in,
                              void* d_out, int out_size, void* d_ws, size_t ws_size,
                              hipStream_t stream) {
  const float* query = (const float*)d_in[0];
  const float* key_  = (const float*)d_in[1];
  const float* value = (const float*)d_in[2];
  const float* wq = (const float*)d_in[3];
  const float* bq = (const float*)d_in[4];
  const float* wk = (const float*)d_in[5];
  const float* bk = (const float*)d_in[6];
  const float* wv = (const float*)d_in[7];
  const float* bv = (const float*)d_in[8];
  const float* wo = (const float*)d_in[9];
  const float* bo = (const float*)d_in[10];
  const float* w1 = (const float*)d_in[11];
  const float* b1 = (const float*)d_in[12];
  const float* w2 = (const float*)d_in[13];
  const float* b2 = (const float*)d_in[14];
  const float* lam = (const float*)d_in[15];
  const float* lng = (const float*)d_in[16];
  const float* lnb = (const float*)d_in[17];

  char* ws = (char*)d_ws;
  size_t off = 0;
  auto alloc = [&](size_t n) { char* p = ws + off; off += (n + 255) & ~(size_t)255; return p; };
  unsigned short* qb  = (unsigned short*)alloc(8388608);   // query bf16 [4096,1024]
  unsigned short* kb  = (unsigned short*)alloc(8388608);
  unsigned short* vb  = (unsigned short*)alloc(8388608);
  unsigned short* wqb = (unsigned short*)alloc(2097152);
  unsigned short* wkb = (unsigned short*)alloc(2097152);
  unsigned short* wvb = (unsigned short*)alloc(2097152);
  unsigned short* wob = (unsigned short*)alloc(2097152);
  unsigned short* w1b = (unsigned short*)alloc(1048576);
  unsigned short* Qp  = (unsigned short*)alloc(8388608);   // projected Q (pre-scaled) bf16
  unsigned short* Kp  = (unsigned short*)alloc(8388608);
  unsigned short* Vt  = (unsigned short*)alloc(8388608);   // V^T bf16 [1024 d_model][4096 tokens]
  float* vadq = (float*)alloc(49152);                      // [4096,3] raw sums (pre-tanh)
  float* vadk = (float*)alloc(49152);
  unsigned short* Obuf = (unsigned short*)alloc(8388608);  // attention out bf16
  // aliases (stream-ordered lifetimes):
  unsigned short* aff  = vb;   // [4][1024 q][1024 k] bf16 (vb dead after proj_k)
  unsigned short* tmpA = qb;   // bf16 [4096,1024] over qb (dead after proj_k)
  unsigned short* tmpB = kb;   // bf16 [4096,1024] over kb (dead after proj_k)

  cvt3_k<<<dim3(2048, 3), 256, 0, stream>>>(query, key_, value, qb, kb, vb, 4194304);
  cvt5_k<<<dim3(512, 5), 256, 0, stream>>>(wq, wk, wv, wo, w1, wqb, wkb, wvb, wob, w1b);
  zero_k<<<24, 256, 0, stream>>>(vadq, vadk);

  // all five projection GEMMs in ONE 1024-block launch (4 blocks/CU); vad layer-2 fused via atomics
  proj_k<<<1024, 256, 0, stream>>>(qb, kb, vb, wqb, wkb, wvb, w1b,
                                   bq, bk, bv, b1, w2, Qp, Kp, Vt, vadq, vadk);
  aff_k<<<dim3(16, 16, 4), 256, 0, stream>>>(vadq, vadk, lam, b2, aff);
  attn_k<<<dim3(8, 16, 4), 512, 0, stream>>>(Qp, Kp, Vt, aff, Obuf);
  wo_k<<<512, 256, 0, stream>>>(Obuf, wob, bo, tmpA, tmpB);
  ln_k<<<4096, 256, 0, stream>>>(query, tmpA, tmpB, lng, lnb, (float*)d_out);
}

// Round 13
// 153.174 us; speedup vs baseline: 1.0332x; 1.0332x over previous
//
#include <hip/hip_runtime.h>
#include <hip/hip_bf16.h>

typedef float f32x4 __attribute__((ext_vector_type(4)));
typedef float f32x16 __attribute__((ext_vector_type(16)));
typedef __bf16 bf16x8 __attribute__((ext_vector_type(8)));
typedef unsigned short us8 __attribute__((ext_vector_type(8)));
typedef unsigned short us4 __attribute__((ext_vector_type(4)));

#define DEVI __device__ __forceinline__
#define LOG2E 1.44269504088896f

DEVI unsigned short f2bf(float x) {
  return __builtin_bit_cast(unsigned short, __float2bfloat16(x));
}
DEVI float bf2f(unsigned short u) {
  return __builtin_bit_cast(float, ((unsigned int)u) << 16);
}
DEVI bf16x8 ldb8(const unsigned short* p) {
  return __builtin_bit_cast(bf16x8, *(const us8*)p);
}
DEVI void gload16(const unsigned short* g, unsigned short* l) {
  __builtin_amdgcn_global_load_lds(
      (const __attribute__((address_space(1))) unsigned int*)(const void*)g,
      (__attribute__((address_space(3))) unsigned int*)(void*)l, 16, 0, 0);
}

// ---------------- fp32 -> bf16 convert: ALL 8 tensors in one flat launch (8448 blocks) ----------------
__global__ __launch_bounds__(256) void cvt_all(const float* __restrict__ q, const float* __restrict__ k,
                                               const float* __restrict__ v,
                                               const float* __restrict__ wq, const float* __restrict__ wk,
                                               const float* __restrict__ wv, const float* __restrict__ wo,
                                               const float* __restrict__ w1,
                                               unsigned short* __restrict__ qb, unsigned short* __restrict__ kb,
                                               unsigned short* __restrict__ vb,
                                               unsigned short* __restrict__ wqb, unsigned short* __restrict__ wkb,
                                               unsigned short* __restrict__ wvb, unsigned short* __restrict__ wob,
                                               unsigned short* __restrict__ w1b) {
  const int bx = blockIdx.x;
  const float* in;
  unsigned short* out;
  int i;
  if (bx < 6144) {                     // q/k/v: 4194304 elems each, 2048 blocks each
    int which = bx >> 11;
    in = which == 0 ? q : which == 1 ? k : v;
    out = which == 0 ? qb : which == 1 ? kb : vb;
    i = ((bx & 2047) * 256 + threadIdx.x) * 8;
  } else if (bx < 8192) {              // wq/wk/wv/wo: 1048576 elems each, 512 blocks each
    int which = (bx - 6144) >> 9;
    in = which == 0 ? wq : which == 1 ? wk : which == 2 ? wv : wo;
    out = which == 0 ? wqb : which == 1 ? wkb : which == 2 ? wvb : wob;
    i = (((bx - 6144) & 511) * 256 + threadIdx.x) * 8;
  } else {                             // w1: 524288 elems, 256 blocks
    in = w1;
    out = w1b;
    i = ((bx - 8192) * 256 + threadIdx.x) * 8;
  }
  float4 a = *(const float4*)(in + i);
  float4 b = *(const float4*)(in + i + 4);
  us8 r = {f2bf(a.x), f2bf(a.y), f2bf(a.z), f2bf(a.w), f2bf(b.x), f2bf(b.y), f2bf(b.z), f2bf(b.w)};
  *(us8*)(out + i) = r;
}

// ---------------- GEMM body (R9/R11-proven): m97 2-phase, BK=64, 32x32x16 MFMA, full row-bit swizzle ----
// Swizzle: physical chunk = logical ^ (row&7) ^ ((row>>3)&3) — measured 0 bank conflicts (R9).
// EPI: 0 = bf16 col-bias; 1 = GELU bf16 col-bias; 2 = bf16 out, col-bias*0.5 (split-K half); 3 = bf16 ROW-bias
template <int EPI>
DEVI void gemm_body(const unsigned short* __restrict__ A, const unsigned short* __restrict__ W,
                    const float* __restrict__ bias, void* __restrict__ Cout,
                    int N, int K, int lda, float oscale, int brow, int bcol,
                    unsigned short* As, unsigned short* Bs, int t) {
  const int l = t & 63;
  const int w4 = t >> 6, wr = w4 >> 1, wc = w4 & 1;
  const int l5 = l & 31, hi = l >> 5;
  f32x16 acc[2][2] = {};
  for (int kt = 0; kt < K; kt += 64) {
    __syncthreads();
#pragma unroll
    for (int i = 0; i < 4; ++i) {
      int c = t + i * 256;                     // 1024 chunks of 16B per operand
      int row = c >> 3;
      int sw = (((c & 7) ^ (row & 7) ^ ((row >> 3) & 3))) * 8;   // inverse-swizzled source
      gload16(A + (size_t)(brow + row) * lda + kt + sw, As + c * 8);
      gload16(W + (size_t)(bcol + row) * lda + kt + sw, Bs + c * 8);
    }
    __syncthreads();
#pragma unroll
    for (int ks = 0; ks < 4; ++ks) {           // 4 k-steps of 16
      bf16x8 af[2], bfr[2];
      const int ch = (ks * 2 + hi) ^ (l5 & 7) ^ ((l5 >> 3) & 3); // swizzled 16B chunk
#pragma unroll
      for (int mi = 0; mi < 2; ++mi)
        af[mi] = ldb8(&As[(wr * 64 + mi * 32 + l5) * 64 + ch * 8]);
#pragma unroll
      for (int ni = 0; ni < 2; ++ni)
        bfr[ni] = ldb8(&Bs[(wc * 64 + ni * 32 + l5) * 64 + ch * 8]);
#pragma unroll
      for (int mi = 0; mi < 2; ++mi)
#pragma unroll
        for (int ni = 0; ni < 2; ++ni)
          acc[mi][ni] = __builtin_amdgcn_mfma_f32_32x32x16_bf16(af[mi], bfr[ni], acc[mi][ni], 0, 0, 0);
    }
  }
  // C/D layout (m74/m101-verified): col = lane&31, row = (reg&3) + 8*(reg>>2) + 4*(lane>>5)
#pragma unroll
  for (int mi = 0; mi < 2; ++mi)
#pragma unroll
    for (int ni = 0; ni < 2; ++ni) {
      int col = bcol + wc * 64 + ni * 32 + l5;
      int rowBase = brow + wr * 64 + mi * 32 + hi * 4;
      float bc = (EPI == 3) ? 0.f : bias[col];
#pragma unroll
      for (int reg = 0; reg < 16; ++reg) {
        int row = rowBase + (reg & 3) + 8 * (reg >> 2);
        float v;
        if (EPI == 3)
          v = (acc[mi][ni][reg] + bias[row]) * oscale;
        else if (EPI == 2)
          v = acc[mi][ni][reg] + 0.5f * bc;
        else
          v = (acc[mi][ni][reg] + bc) * oscale;
        if (EPI == 1) v = 0.5f * v * (1.0f + erff(v * 0.70710678118f));
        ((unsigned short*)Cout)[(size_t)row * N + col] = f2bf(v);
      }
    }
}

// ---------------- fused projections: Q-proj | K-proj | V^T | h1q | h1k in one 1024-block launch ----------------
__global__ __launch_bounds__(256) void proj_k(const unsigned short* __restrict__ qb, const unsigned short* __restrict__ kb,
                                              const unsigned short* __restrict__ vb,
                                              const unsigned short* __restrict__ wqb, const unsigned short* __restrict__ wkb,
                                              const unsigned short* __restrict__ wvb, const unsigned short* __restrict__ w1b,
                                              const float* __restrict__ bq, const float* __restrict__ bk,
                                              const float* __restrict__ bv, const float* __restrict__ b1,
                                              unsigned short* __restrict__ Qp, unsigned short* __restrict__ Kp,
                                              unsigned short* __restrict__ Vt,
                                              unsigned short* __restrict__ h1q, unsigned short* __restrict__ h1k) {
  __shared__ unsigned short As[8192];
  __shared__ unsigned short Bs[8192];
  const int t = threadIdx.x;
  const int lin = blockIdx.x;                 // 1024 blocks
  const int nl = (lin & 7) * 128 + (lin >> 3);  // XCD swizzle: each XCD gets one contiguous range
  if (nl < 256) {        // Q projection (pre-scaled by SCALE*log2e), 8x32
    gemm_body<0>(qb, wqb, bq, Qp, 1024, 1024, 1024, 0.125f * LOG2E,
                 (nl >> 3) * 128, (nl & 7) * 128, As, Bs, t);
  } else if (nl < 512) { // K projection, 8x32
    int s = nl - 256;
    gemm_body<0>(kb, wkb, bk, Kp, 1024, 1024, 1024, 1.f,
                 (s >> 3) * 128, (s & 7) * 128, As, Bs, t);
  } else if (nl < 768) { // V^T = Wv @ X^T (row-bias), 32x8
    int s = nl - 512;
    gemm_body<3>(wvb, vb, bv, Vt, 4096, 1024, 1024, 1.f,
                 (s >> 5) * 128, (s & 31) * 128, As, Bs, t);
  } else {               // VAD layer 1 (GELU) for query / key, 4x32 x2
    int s = nl - 768;
    const unsigned short* A = (s >= 128) ? kb : qb;
    unsigned short* C = (s >= 128) ? h1k : h1q;
    int s2 = s & 127;
    gemm_body<1>(A, w1b, b1, C, 512, 1024, 1024, 1.f,
                 (s2 >> 2) * 128, (s2 & 3) * 128, As, Bs, t);
  }
}

// ---------------- Wo GEMM, split-K x2 (512 blocks), bf16 partial outputs ----------------
__global__ __launch_bounds__(256) void wo_k(const unsigned short* __restrict__ Obuf, const unsigned short* __restrict__ wob,
                                            const float* __restrict__ bo,
                                            unsigned short* __restrict__ tmpA, unsigned short* __restrict__ tmpB) {
  __shared__ unsigned short As[8192];
  __shared__ unsigned short Bs[8192];
  const int t = threadIdx.x;
  const int lin = blockIdx.x;                 // 512 blocks
  const int nl = (lin & 7) * 64 + (lin >> 3);
  const int z = nl >> 8, s = nl & 255;
  gemm_body<2>(Obuf + z * 512, wob + z * 512, bo, z ? tmpB : tmpA,
               1024, 512, 1024, 1.f, (s >> 3) * 128, (s & 7) * 128, As, Bs, t);
}

// ---------------- VAD layer 2 (batched grid.y) ----------------
__global__ __launch_bounds__(256) void vad2_k(const unsigned short* __restrict__ h1a, const unsigned short* __restrict__ h1b,
                                              const float* __restrict__ w2, const float* __restrict__ b2,
                                              float* __restrict__ outa, float* __restrict__ outb) {
  const unsigned short* h1 = blockIdx.y ? h1b : h1a;
  float* out = blockIdx.y ? outb : outa;
  const int t = threadIdx.x, l = t & 63, w = t >> 6;
  const int row = blockIdx.x * 4 + w;
  us8 hv = *(const us8*)(h1 + (size_t)row * 512 + l * 8);
  float hf[8];
#pragma unroll
  for (int j = 0; j < 8; ++j) hf[j] = bf2f(hv[j]);
  float s[3];
#pragma unroll
  for (int c = 0; c < 3; ++c) {
    const float* wp = w2 + c * 512 + l * 8;
    float a = 0.f;
#pragma unroll
    for (int j = 0; j < 8; ++j) a += hf[j] * wp[j];
    s[c] = a;
  }
#pragma unroll
  for (int m = 1; m < 64; m <<= 1) {
#pragma unroll
    for (int c = 0; c < 3; ++c) s[c] += __shfl_xor(s[c], m, 64);
  }
  if (l == 0) {
#pragma unroll
    for (int c = 0; c < 3; ++c) out[(size_t)row * 3 + c] = tanhf(s[c] + b2[c]);
  }
}

// ---------------- affinity precompute, q-major + log2e-scaled: aff[b][q][k] ----------------
__global__ __launch_bounds__(256) void aff_k(const float* __restrict__ vq, const float* __restrict__ vk,
                                             const float* __restrict__ plam, unsigned short* __restrict__ aff) {
  __shared__ float vqs[64][3], vks[64][3];
  const int t = threadIdx.x;
  const int b = blockIdx.z, q0 = blockIdx.y * 64, k0 = blockIdx.x * 64;
  const float lam2 = plam[0] * LOG2E;
  if (t < 192) {
    ((float*)vqs)[t] = vq[((size_t)b * 1024 + q0) * 3 + t];
    ((float*)vks)[t] = vk[((size_t)b * 1024 + k0) * 3 + t];
  }
  __syncthreads();
  const int q = t >> 2, kc = (t & 3) * 16;
  const float a0 = vqs[q][0], a1 = vqs[q][1], a2 = vqs[q][2];
  unsigned short o[16];
#pragma unroll
  for (int j = 0; j < 16; ++j) {
    int k = kc + j;
    float dx = a0 - vks[k][0], dy = a1 - vks[k][1], dz = a2 - vks[k][2];
    o[j] = f2bf(-lam2 * sqrtf(dx * dx + dy * dy + dz * dz));
  }
  unsigned short* dst = aff + ((size_t)(b * 1024 + q0 + q)) * 1024 + k0 + kc;
  *(us8*)dst = *(us8*)&o[0];
  *(us8*)(dst + 8) = *(us8*)&o[8];
}

// ---------------- flash attention: QBLK=128, no-max exp2 softmax, aff as C-init; 3 blocks/CU ----------------
__global__ __launch_bounds__(512, 6) void attn_k(const unsigned short* __restrict__ Qp,
                                                 const unsigned short* __restrict__ Kp,
                                                 const unsigned short* __restrict__ Vt,
                                                 const unsigned short* __restrict__ aff,
                                                 unsigned short* __restrict__ Obuf) {
  __shared__ unsigned short Ks[2][4096];   // [64][64] bf16, chunk ^= row&7
  __shared__ unsigned short Vs[2][4096];   // logical [d][token]
  __shared__ unsigned short Ps[8][1024];   // per-wave [16 q-rows][64 k], 16B-chunk XOR-swizzled
  const int lin = blockIdx.x + 8 * (blockIdx.y + 16 * blockIdx.z);  // 512 blocks, grid (8,16,4)
  const int nl = (lin & 7) * 64 + (lin >> 3);  // XCD swizzle (512 = 8*64, bijective)
  const int qb = nl & 7, h = (nl >> 3) & 15, b = nl >> 7;
  const int t = threadIdx.x, l = t & 63, w = t >> 6;   // w in 0..7
  const int l4 = l & 15, lg = l >> 4;
  const size_t qrow0 = (size_t)b * 1024 + qb * 128;
  const int hoff = h * 64;

  // Q fragments straight to registers (read-once). Used as MFMA *B*-operand (swapped QK^T).
  bf16x8 qf[2];
#pragma unroll
  for (int ks = 0; ks < 2; ++ks)
    qf[ks] = ldb8(Qp + (qrow0 + w * 16 + l4) * 1024 + hoff + ks * 32 + lg * 8);

  // prologue: stage K/V tile 0 (512 threads -> 1 chunk each per operand)
  {
    const unsigned short* gk = Kp + ((size_t)b * 1024) * 1024 + hoff;
    const unsigned short* gv = Vt + (size_t)hoff * 4096 + (size_t)b * 1024;
    int c = t, row = c >> 3, sw = ((c & 7) ^ (row & 7)) * 8;
    gload16(gk + (size_t)row * 1024 + sw, Ks[0] + c * 8);
    gload16(gv + (size_t)row * 4096 + sw, Vs[0] + c * 8);
  }
  float l_run = 0.f;   // per-lane partial denominator (this lane's 16 k-columns per tile)
  f32x4 accO[4] = {};
  const unsigned short* ab = aff + (qrow0 + w * 16 + l4) * 1024 + lg * 4;
  __syncthreads();

  int cur = 0;
  for (int kt = 0; kt < 16; ++kt) {
    // issue next-tile stage FIRST: latency hides under this tile's compute
    if (kt < 15) {
      const unsigned short* gk = Kp + ((size_t)b * 1024 + (kt + 1) * 64) * 1024 + hoff;
      const unsigned short* gv = Vt + (size_t)hoff * 4096 + (size_t)b * 1024 + (kt + 1) * 64;
      int c = t, row = c >> 3, sw = ((c & 7) ^ (row & 7)) * 8;
      gload16(gk + (size_t)row * 1024 + sw, Ks[cur ^ 1] + c * 8);
      gload16(gv + (size_t)row * 4096 + sw, Vs[cur ^ 1] + c * 8);
    }
    // QK^T with SWAPPED operands, affinity as C-initializer:
    f32x4 sc[4];
#pragma unroll
    for (int jt = 0; jt < 4; ++jt) {
      us4 av = *(const us4*)(ab + kt * 64 + jt * 16);
#pragma unroll
      for (int r = 0; r < 4; ++r) sc[jt][r] = bf2f(av[r]);
    }
    __builtin_amdgcn_s_setprio(1);
#pragma unroll
    for (int jt = 0; jt < 4; ++jt) {
#pragma unroll
      for (int ks = 0; ks < 2; ++ks) {
        bf16x8 kf = ldb8(&Ks[cur][(jt * 16 + l4) * 64 + (((ks * 4 + lg) ^ (l4 & 7))) * 8]);
        sc[jt] = __builtin_amdgcn_mfma_f32_16x16x32_bf16(kf, qf[ks], sc[jt], 0, 0, 0);
      }
    }
    __builtin_amdgcn_s_setprio(0);
    // no-max softmax: scores bounded -> exp2 directly, f32-safe
    float pv[4][4];
    float rs = 0.f;
#pragma unroll
    for (int jt = 0; jt < 4; ++jt)
#pragma unroll
      for (int r = 0; r < 4; ++r) { pv[jt][r] = exp2f(sc[jt][r]); rs += pv[jt][r]; }
    l_run += rs;
    // pack P to bf16 pairs, swizzled ds_write_b64 into Ps[w][q=l4][k]
    char* pw = (char*)&Ps[w][0];
#pragma unroll
    for (int jt = 0; jt < 4; ++jt) {
      unsigned int p0, p1;
      asm("v_cvt_pk_bf16_f32 %0, %1, %2" : "=v"(p0) : "v"(pv[jt][0]), "v"(pv[jt][1]));
      asm("v_cvt_pk_bf16_f32 %0, %1, %2" : "=v"(p1) : "v"(pv[jt][2]), "v"(pv[jt][3]));
      int chunk = (jt * 2 + (lg >> 1)) ^ (l4 & 7);
      *(unsigned long long*)(pw + l4 * 128 + chunk * 16 + (lg & 1) * 8) =
          (unsigned long long)p0 | ((unsigned long long)p1 << 32);
    }
    // PV: A-frag from Ps (row=l4, k=lg*8+j), B-frag from transposed V
    __builtin_amdgcn_s_setprio(1);
#pragma unroll
    for (int js = 0; js < 2; ++js) {
      bf16x8 pa = ldb8(&Ps[w][l4 * 64 + (((js * 4 + lg) ^ (l4 & 7))) * 8]);
#pragma unroll
      for (int dt = 0; dt < 4; ++dt) {
        bf16x8 vf = ldb8(&Vs[cur][(dt * 16 + l4) * 64 + (((js * 4 + lg) ^ (l4 & 7))) * 8]);
        accO[dt] = __builtin_amdgcn_mfma_f32_16x16x32_bf16(pa, vf, accO[dt], 0, 0, 0);
      }
    }
    __builtin_amdgcn_s_setprio(0);
    __syncthreads();  // single barrier per tile
    cur ^= 1;
  }
  // epilogue: reduce denominator across lg groups, transpose to accO's q-domain, normalize
  l_run += __shfl_xor(l_run, 16, 64);
  l_run += __shfl_xor(l_run, 32, 64);
  float linv = 1.f / l_run;
  float lr[4];
#pragma unroll
  for (int r = 0; r < 4; ++r) lr[r] = __shfl(linv, lg * 4 + r, 16);
#pragma unroll
  for (int dt = 0; dt < 4; ++dt)
#pragma unroll
    for (int r = 0; r < 4; ++r) {
      float v = accO[dt][r] * lr[r];
      Obuf[(qrow0 + w * 16 + lg * 4 + r) * 1024 + hoff + dt * 16 + l4] = f2bf(v);
    }
}

// ---------------- residual + layernorm (query fp32 + bf16 partials tmpA + tmpB) ----------------
__global__ __launch_bounds__(256) void ln_k(const float* __restrict__ q,
                                            const unsigned short* __restrict__ ta,
                                            const unsigned short* __restrict__ tb,
                                            const float* __restrict__ g,
                                            const float* __restrict__ bb,
                                            float* __restrict__ out) {
  __shared__ float red[8];
  const int row = blockIdx.x, t = threadIdx.x;
  const int l = t & 63, w = t >> 6;
  const size_t base = (size_t)row * 1024 + t * 4;
  float4 a = *(const float4*)(q + base);
  us4 cv = *(const us4*)(ta + base);
  us4 dv = *(const us4*)(tb + base);
  float x0 = a.x + bf2f(cv[0]) + bf2f(dv[0]);
  float x1 = a.y + bf2f(cv[1]) + bf2f(dv[1]);
  float x2 = a.z + bf2f(cv[2]) + bf2f(dv[2]);
  float x3 = a.w + bf2f(cv[3]) + bf2f(dv[3]);
  float s = x0 + x1 + x2 + x3;
#pragma unroll
  for (int m = 1; m < 64; m <<= 1) s += __shfl_xor(s, m, 64);
  if (l == 0) red[w] = s;
  __syncthreads();
  float mean = (red[0] + red[1] + red[2] + red[3]) * (1.f / 1024.f);
  float d0 = x0 - mean, d1 = x1 - mean, d2 = x2 - mean, d3 = x3 - mean;
  float v = d0 * d0 + d1 * d1 + d2 * d2 + d3 * d3;
#pragma unroll
  for (int m = 1; m < 64; m <<= 1) v += __shfl_xor(v, m, 64);
  if (l == 0) red[4 + w] = v;
  __syncthreads();
  float var = (red[4] + red[5] + red[6] + red[7]) * (1.f / 1024.f);
  float rstd = rsqrtf(var + 1e-5f);
  float4 gv = *(const float4*)(g + t * 4);
  float4 bv = *(const float4*)(bb + t * 4);
  float4 o;
  o.x = d0 * rstd * gv.x + bv.x;
  o.y = d1 * rstd * gv.y + bv.y;
  o.z = d2 * rstd * gv.z + bv.z;
  o.w = d3 * rstd * gv.w + bv.w;
  *(float4*)(out + (size_t)row * 1024 + t * 4) = o;
}

extern "C" void kernel_launch(void* const* d_in, const int* in_sizes, int n_in,
                              void* d_out, int out_size, void* d_ws, size_t ws_size,
                              hipStream_t stream) {
  const float* query = (const float*)d_in[0];
  const float* key_  = (const float*)d_in[1];
  const float* value = (const float*)d_in[2];
  const float* wq = (const float*)d_in[3];
  const float* bq = (const float*)d_in[4];
  const float* wk = (const float*)d_in[5];
  const float* bk = (const float*)d_in[6];
  const float* wv = (const float*)d_in[7];
  const float* bv = (const float*)d_in[8];
  const float* wo = (const float*)d_in[9];
  const float* bo = (const float*)d_in[10];
  const float* w1 = (const float*)d_in[11];
  const float* b1 = (const float*)d_in[12];
  const float* w2 = (const float*)d_in[13];
  const float* b2 = (const float*)d_in[14];
  const float* lam = (const float*)d_in[15];
  const float* lng = (const float*)d_in[16];
  const float* lnb = (const float*)d_in[17];

  char* ws = (char*)d_ws;
  size_t off = 0;
  auto alloc = [&](size_t n) { char* p = ws + off; off += (n + 255) & ~(size_t)255; return p; };
  unsigned short* qb  = (unsigned short*)alloc(8388608);   // query bf16 [4096,1024]
  unsigned short* kb  = (unsigned short*)alloc(8388608);
  unsigned short* vb  = (unsigned short*)alloc(8388608);
  unsigned short* wqb = (unsigned short*)alloc(2097152);
  unsigned short* wkb = (unsigned short*)alloc(2097152);
  unsigned short* wvb = (unsigned short*)alloc(2097152);
  unsigned short* wob = (unsigned short*)alloc(2097152);
  unsigned short* w1b = (unsigned short*)alloc(1048576);
  unsigned short* Qp  = (unsigned short*)alloc(8388608);   // projected Q (pre-scaled) bf16
  unsigned short* Kp  = (unsigned short*)alloc(8388608);
  unsigned short* Vt  = (unsigned short*)alloc(8388608);   // V^T bf16 [1024 d_model][4096 tokens]
  unsigned short* h1q = (unsigned short*)alloc(4194304);   // gelu(x@w1^T) bf16 [4096,512]
  unsigned short* h1k = (unsigned short*)alloc(4194304);
  float* vadq = (float*)alloc(49152);                      // [4096,3] tanh'd
  float* vadk = (float*)alloc(49152);
  unsigned short* Obuf = (unsigned short*)alloc(8388608);  // attention out bf16
  // aliases (stream-ordered lifetimes):
  unsigned short* aff  = vb;   // [4][1024 q][1024 k] bf16 (vb dead after proj_k)
  unsigned short* tmpA = qb;   // bf16 [4096,1024] over qb (dead after proj_k)
  unsigned short* tmpB = kb;   // bf16 [4096,1024] over kb (dead after proj_k)

  cvt_all<<<8448, 256, 0, stream>>>(query, key_, value, wq, wk, wv, wo, w1,
                                    qb, kb, vb, wqb, wkb, wvb, wob, w1b);

  // all five projection GEMMs in ONE 1024-block launch (4 blocks/CU)
  proj_k<<<1024, 256, 0, stream>>>(qb, kb, vb, wqb, wkb, wvb, w1b,
                                   bq, bk, bv, b1, Qp, Kp, Vt, h1q, h1k);
  vad2_k<<<dim3(1024, 2), 256, 0, stream>>>(h1q, h1k, w2, b2, vadq, vadk);
  aff_k<<<dim3(16, 16, 4), 256, 0, stream>>>(vadq, vadk, lam, aff);
  attn_k<<<dim3(8, 16, 4), 512, 0, stream>>>(Qp, Kp, Vt, aff, Obuf);
  wo_k<<<512, 256, 0, stream>>>(Obuf, wob, bo, tmpA, tmpB);
  ln_k<<<4096, 256, 0, stream>>>(query, tmpA, tmpB, lng, lnb, (float*)d_out);
}